// Round 18
// baseline (93.867 us; speedup 1.0000x reference)
//
#include <hip/hip_runtime.h>

// Mutihead_Attention: x,y [2,2048,512] f32. Flat-reshape => head-batch hb owns
// contiguous [2048,64] chunk at hb*131072 of each [4096,512] projection.
// scores=QK^T/sqrt(512); mask score<=rowmean; softmax; PV; @o_w^T+o_b.
// rowmean_i = q_i.ksum/2048 (ksum fused in K-proj epilogue, f32 acc).
// R18: attn dependency-latency attack (issue-sum ~1660 cyc/iter vs measured
// ~5850 at 2 waves/SIMD => ~4200 stall cyc; QK^T chain was 8 MFMA deep, PV 4).
// 4-chain QK^T (s0h/s0l/s1h/s1l, depth 8->4; merge = 1 add/score at exp) and
// dual-O PV chains (O0a/O0b/O1a/O1b, depth 4->2; merged once after k-loop).
// Pure f32-order reorder -- numerics unchanged (absmax 4.64e-3 from R17's
// plain-bf16 K; error budget derivation in R17 notes).

typedef unsigned short ushort;
typedef unsigned int uint;

typedef __bf16  bf16x8   __attribute__((ext_vector_type(8)));
typedef float   floatx4  __attribute__((ext_vector_type(4)));
typedef float   floatx16 __attribute__((ext_vector_type(16)));
typedef float   float4v  __attribute__((ext_vector_type(4)));
typedef uint    uint4v   __attribute__((ext_vector_type(4)));
typedef ushort  ushort4v __attribute__((ext_vector_type(4)));

#define MFMA16(a,b,c) __builtin_amdgcn_mfma_f32_16x16x32_bf16((a),(b),(c),0,0,0)
#define MFMA32(a,b,c) __builtin_amdgcn_mfma_f32_32x32x16_bf16((a),(b),(c),0,0,0)

__device__ __forceinline__ float b2f(ushort u){
  union { uint i; float f; } v; v.i = ((uint)u) << 16; return v.f;
}
__device__ __forceinline__ ushort f2b(float f){   // RNE f32->bf16
  union { float f; uint i; } v; v.f = f;
  uint r = v.i + 0x7FFFu + ((v.i >> 16) & 1u);
  return (ushort)(r >> 16);
}
__device__ __forceinline__ void split2(float f, ushort& h, ushort& l){
  h = f2b(f);
  l = f2b(f - b2f(h));
}
__device__ __forceinline__ void gload16(const ushort* g, ushort* l){
  __builtin_amdgcn_global_load_lds(
      (const __attribute__((address_space(1))) unsigned int*)g,
      (__attribute__((address_space(3))) unsigned int*)l, 16, 0, 0);
}

// ---------------------------------------------------------------------------
// One-time f32 -> bf16 converters, all inputs in one launch.
// ---------------------------------------------------------------------------
__global__ __launch_bounds__(256) void split_all(
    const float* __restrict__ x, const float* __restrict__ y,
    const float* __restrict__ qw, const float* __restrict__ kw,
    const float* __restrict__ vw, const float* __restrict__ ow,
    ushort* __restrict__ xhi, ushort* __restrict__ xlo,
    ushort* __restrict__ yhi, ushort* __restrict__ ylo,
    ushort* __restrict__ qwh, ushort* __restrict__ qwl,
    ushort* __restrict__ kwh, ushort* __restrict__ kwl,
    ushort* __restrict__ vwh, ushort* __restrict__ owh)
{
  int idx = blockIdx.x * 256 + threadIdx.x;       // 1,310,720 float4s total
  if (idx < 1048576){
    const float* sp; ushort *hp, *lp; int i;
    if (idx < 524288){ sp = x; hp = xhi; lp = xlo; i = idx; }
    else             { sp = y; hp = yhi; lp = ylo; i = idx - 524288; }
    float4v d = ((const float4v*)sp)[i];
    ushort4v h, l;
    #pragma unroll
    for (int j=0;j<4;j++){ ushort hh,ll; split2(d[j],hh,ll); h[j]=hh; l[j]=ll; }
    ((ushort4v*)hp)[i] = h;
    ((ushort4v*)lp)[i] = l;
  } else {
    int k = idx - 1048576;                        // 0..262143
    int a = k >> 16, i = k & 65535;
    if (a < 2){
      const float* sp = a ? kw : qw;
      ushort *hp = a ? kwh : qwh, *lp = a ? kwl : qwl;
      float4v d = ((const float4v*)sp)[i];
      ushort4v h, l;
      #pragma unroll
      for (int j=0;j<4;j++){ ushort hh,ll; split2(d[j],hh,ll); h[j]=hh; l[j]=ll; }
      ((ushort4v*)hp)[i] = h;
      ((ushort4v*)lp)[i] = l;
    } else {
      const float* sp = (a == 2) ? vw : ow;
      ushort *hp = (a == 2) ? vwh : owh;
      float4v d = ((const float4v*)sp)[i];
      ushort4v h;
      #pragma unroll
      for (int j=0;j<4;j++) h[j] = f2b(d[j]);
      ((ushort4v*)hp)[i] = h;
    }
  }
}

// ---------------------------------------------------------------------------
// Q/K/V projections in ONE dispatch. grid 1536: seg = id>>9 (0=Q,1=K,2=V).
// seg 0: split x split (3 MFMA), hi/lo out. seg 1: split x split, PLAIN bf16
// out + fused ksum (f32 acc). seg 2: plain x plain (1 MFMA), bf16 out.
// BM=64 BN=64 BK=64, XCD swizzle, dbuf, gload_lds(16), row&7 XOR swizzle.
// ---------------------------------------------------------------------------
__global__ __launch_bounds__(256) void proj_qkv(
    const ushort* __restrict__ xhi, const ushort* __restrict__ xlo,
    const ushort* __restrict__ yhi, const ushort* __restrict__ ylo,
    const ushort* __restrict__ qwh, const ushort* __restrict__ qwl,
    const ushort* __restrict__ kwh, const ushort* __restrict__ kwl,
    const ushort* __restrict__ vwh,
    const float* __restrict__ q_b, const float* __restrict__ k_b,
    const float* __restrict__ v_b,
    ushort* __restrict__ pq_hi, ushort* __restrict__ pq_lo,
    ushort* __restrict__ pk,
    ushort* __restrict__ pv, float* __restrict__ ksum_out)
{
  const int seg = blockIdx.x >> 9;
  const int id  = blockIdx.x & 511;
  const int m0 = ((id & 7) * 8 + ((id >> 3) & 7)) * 64;
  const int n0 = (id >> 6) * 64;
  const bool split = (seg < 2);

  const ushort* Ahi = (seg == 0) ? xhi : yhi;
  const ushort* Alo = (seg == 0) ? xlo : ylo;
  const ushort* Bhi = (seg == 0) ? qwh : ((seg == 1) ? kwh : vwh);
  const ushort* Blo = (seg == 0) ? qwl : kwl;
  const float*  bias = (seg == 0) ? q_b : ((seg == 1) ? k_b : v_b);
  ushort* outhi = (seg == 0) ? pq_hi : ((seg == 1) ? pk : pv);
  ushort* outlo = pq_lo;                       // used only by seg 0

  __shared__ __align__(16) ushort AH[2][4096];                 // [64][64]
  __shared__ __align__(16) ushort AL[2][4096];
  __shared__ __align__(16) ushort BH[2][4096];
  __shared__ __align__(16) ushort BL[2][4096];
  __shared__ float cs[64];

  const int t    = threadIdx.x;
  const int lane = t & 63;
  const int w    = t >> 6;
  const int wm   = w >> 1, wn = w & 1;
  const int lr   = lane & 15, lg = lane >> 4;

  const int rl  = lane >> 3;
  const int c8s = (lane & 7) ^ rl;       // pre-swizzled source 16B block

  auto stage = [&](int buf, int k0){
    if (split){
      #pragma unroll
      for (int j = 0; j < 8; j++){
        const int c = w * 8 + j;
        if (c < 8)
          gload16(Ahi + (size_t)(m0 + c*8 + rl)*512 + k0 + c8s*8, &AH[buf][c*512]);
        else if (c < 16)
          gload16(Alo + (size_t)(m0 + (c-8)*8 + rl)*512 + k0 + c8s*8, &AL[buf][(c-8)*512]);
        else if (c < 24)
          gload16(Bhi + (size_t)(n0 + (c-16)*8 + rl)*512 + k0 + c8s*8, &BH[buf][(c-16)*512]);
        else
          gload16(Blo + (size_t)(n0 + (c-24)*8 + rl)*512 + k0 + c8s*8, &BL[buf][(c-24)*512]);
      }
    } else {
      #pragma unroll
      for (int j = 0; j < 4; j++){
        const int c = w * 4 + j;
        if (c < 8)
          gload16(Ahi + (size_t)(m0 + c*8 + rl)*512 + k0 + c8s*8, &AH[buf][c*512]);
        else
          gload16(Bhi + (size_t)(n0 + (c-8)*8 + rl)*512 + k0 + c8s*8, &BH[buf][(c-8)*512]);
      }
    }
  };

  floatx4 zf; zf[0]=0.f; zf[1]=0.f; zf[2]=0.f; zf[3]=0.f;
  floatx4 acc[2][2];
  #pragma unroll
  for (int i=0;i<2;i++)
    #pragma unroll
    for (int j=0;j<2;j++) acc[i][j] = zf;

  stage(0, 0);
  __syncthreads();

  int cur = 0;
  for (int it = 0; it < 8; ++it){
    if (it < 7) stage(cur^1, (it+1)*64);

    #pragma unroll
    for (int ks=0; ks<2; ks++){
      const int xo = ((ks*4 + lg) ^ (lr & 7)) << 3;
      bf16x8 ah[2], al[2], bh[2], bl[2];
      #pragma unroll
      for (int mi=0;mi<2;mi++){
        const int off = (wm*32 + mi*16 + lr)*64 + xo;
        ah[mi] = *(const bf16x8*)&AH[cur][off];
        if (split) al[mi] = *(const bf16x8*)&AL[cur][off];
      }
      #pragma unroll
      for (int ni=0;ni<2;ni++){
        const int off = (wn*32 + ni*16 + lr)*64 + xo;
        bh[ni] = *(const bf16x8*)&BH[cur][off];
        if (split) bl[ni] = *(const bf16x8*)&BL[cur][off];
      }
      #pragma unroll
      for (int mi=0;mi<2;mi++)
        #pragma unroll
        for (int ni=0;ni<2;ni++){
          acc[mi][ni] = MFMA16(ah[mi], bh[ni], acc[mi][ni]);
          if (split){
            acc[mi][ni] = MFMA16(ah[mi], bl[ni], acc[mi][ni]);
            acc[mi][ni] = MFMA16(al[mi], bh[ni], acc[mi][ni]);
          }
        }
    }
    __syncthreads();
    cur ^= 1;
  }

  // epilogue: D frag -> m = lg*4+r, n = lr
  #pragma unroll
  for (int ni=0;ni<2;ni++){
    const int n = n0 + wn*32 + ni*16 + lr;
    const float bn = bias[n];
    #pragma unroll
    for (int mi=0;mi<2;mi++){
      #pragma unroll
      for (int r=0;r<4;r++){
        const int m = m0 + wm*32 + mi*16 + lg*4 + r;
        const float c = acc[mi][ni][r] + bn;
        const size_t off = (size_t)m*512 + n;
        if (seg == 0){ ushort h,l; split2(c,h,l); outhi[off]=h; outlo[off]=l; }
        else         { outhi[off] = f2b(c); }
      }
    }
  }

  if (seg == 1) {
    if (t < 64) cs[t] = 0.f;
    __syncthreads();
    #pragma unroll
    for (int ni=0;ni<2;ni++){
      float s = 0.f;
      #pragma unroll
      for (int mi=0;mi<2;mi++)
        #pragma unroll
        for (int r=0;r<4;r++) s += acc[mi][ni][r];
      atomicAdd(&cs[wn*32 + ni*16 + lr], s);
    }
    __syncthreads();
    if (t < 64){
      const int hb = m0 >> 8;
      atomicAdd(&ksum_out[hb*64 + t], cs[t] + 64.f * bias[n0 + t]);
    }
  }
}

// ---------------------------------------------------------------------------
// vt[hb][d][s] = pv_chunk[hb][s][d]  (64x64 LDS-tiled transpose)
// ---------------------------------------------------------------------------
__global__ __launch_bounds__(256) void vtrans(
    const ushort* __restrict__ pv, ushort* __restrict__ vt)
{
  const int hb = blockIdx.y;
  const int s0 = blockIdx.x * 64;
  const size_t cb = (size_t)hb * 131072;
  __shared__ __align__(16) ushort T[64][68];
  const int t = threadIdx.x;
  {
    int s = t >> 2, c = (t & 3) * 16;
    *(uint4v*)&T[s][c]     = *(const uint4v*)&pv[cb + (size_t)(s0+s)*64 + c];
    *(uint4v*)&T[s][c + 8] = *(const uint4v*)&pv[cb + (size_t)(s0+s)*64 + c + 8];
  }
  __syncthreads();
  const int d = t >> 2, sc = (t & 3) * 16;
  ushort buf[16];
  #pragma unroll
  for (int i=0;i<16;i++) buf[i] = T[sc + i][d];
  *(uint4v*)&vt[cb + (size_t)d*2048 + s0 + sc]     = *(const uint4v*)&buf[0];
  *(uint4v*)&vt[cb + (size_t)d*2048 + s0 + sc + 8] = *(const uint4v*)&buf[8];
}

// ---------------------------------------------------------------------------
// Fused attention (R17 structure + 4-chain QK^T / dual-O PV ILP):
// 128 q-rows/block, 8 waves = 4 q-groups (32 q, 32x32x16 swapped QK^T) x
// 2 kv-halves. KH/VT dbuf in 64KB LDS, single barrier/tile. K plain bf16,
// Q split hi/lo. Cross-half (O,z) combine in LDS; normalize in-kernel.
// ---------------------------------------------------------------------------
__device__ __forceinline__ void stage_tile(
    ushort* khb, ushort* vtb,
    const ushort* gk, const ushort* gvt,
    size_t cb, int kvb, int ws, int l)
{
  const int rsub = l >> 3;
  const int c8   = (l & 7) ^ rsub;
  #pragma unroll
  for (int j = 0; j < 4; j++){
    const int chunk = ws*4 + j;       // 16 x 1KB: 8 KH, 8 VT
    const int a   = chunk >> 3;
    const int sub = chunk & 7;
    const int row = sub*8 + rsub;
    if (a == 0)
      gload16(gk  + cb + (size_t)(kvb + row)*64 + c8*8, khb + sub*512);
    else
      gload16(gvt + cb + (size_t)row*2048 + kvb + c8*8, vtb + sub*512);
  }
}

__global__ __launch_bounds__(512) void attn_kernel(
    const ushort* __restrict__ qhi, const ushort* __restrict__ qlo,
    const ushort* __restrict__ kbf,
    const ushort* __restrict__ vt,  const float* __restrict__ ksum,
    ushort* __restrict__ attno)
{
  const int id = blockIdx.x;                      // XCD swizzle: 2 hb per XCD
  const int hb = ((id & 7) << 1) | ((id >> 3) & 1);
  const int q0 = (id >> 4) * 128;
  const size_t cb = (size_t)hb * 131072;
  const float C1 = 0.04419417382415922f * 1.44269504088896f;  // NF*log2(e)

  __shared__ __align__(16) ushort TILES[2][2][2][4096];  // [half][buf][KH,VT]

  const int t = threadIdx.x, l = t & 63, w = t >> 6;
  const int half = w >> 2, ws = w & 3;
  const int lq = l & 31, h = l >> 5;
  const int kbase = half * 1024;

  stage_tile(TILES[half][0][0], TILES[half][0][1],
             kbf, vt, cb, kbase, ws, l);

  // Q frags (swapped-B operand): lane holds Q[q = lq][d = st*16 + h*8 + 0..7]
  union U8 { bf16x8 v; ushort u[8]; };
  U8 qfh[4], qfl[4];
  float part = 0.f;
  #pragma unroll
  for (int st=0; st<4; st++){
    size_t g = cb + (size_t)(q0 + ws*32 + lq)*64 + st*16 + h*8;
    qfh[st].v = *(const bf16x8*)&qhi[g];
    qfl[st].v = *(const bf16x8*)&qlo[g];
    float4v k0 = *(const float4v*)&ksum[hb*64 + st*16 + h*8];
    float4v k1 = *(const float4v*)&ksum[hb*64 + st*16 + h*8 + 4];
    #pragma unroll
    for (int j=0;j<4;j++) part += (b2f(qfh[st].u[j])   + b2f(qfl[st].u[j]))   * k0[j];
    #pragma unroll
    for (int j=0;j<4;j++) part += (b2f(qfh[st].u[4+j]) + b2f(qfl[st].u[4+j])) * k1[j];
  }
  part += __shfl_xor(part, 32);            // both d-halves
  const float rm = part * (1.f/2048.f);    // raw row mean for q = lq
  const float nrmc = -rm * C1;

  floatx16 O0a = {0,0,0,0,0,0,0,0,0,0,0,0,0,0,0,0};
  floatx16 O0b = O0a, O1a = O0a, O1b = O0a;
  float za = 0.f, zb = 0.f;

  __syncthreads();                          // tile 0 staged

  int cur = 0;
  for (int kt = 0; kt < 16; kt++){
    if (kt + 1 < 16)
      stage_tile(TILES[half][cur^1][0], TILES[half][cur^1][1],
                 kbf, vt, cb, kbase + (kt+1)*64, ws, l);

    const ushort* KHc = TILES[half][cur][0];
    const ushort* VTc = TILES[half][cur][1];

    // QK^T swapped: 4 independent accumulator chains (depth 4 each)
    floatx16 s0h = {0,0,0,0,0,0,0,0,0,0,0,0,0,0,0,0};
    floatx16 s0l = s0h, s1h = s0h, s1l = s0h;
    #pragma unroll
    for (int st=0; st<4; st++){
      const int xo = (((st*2 + h) ^ (lq & 7)) << 3);
      bf16x8 kh0 = *(const bf16x8*)&KHc[(lq     )*64 + xo];
      bf16x8 kh1 = *(const bf16x8*)&KHc[(32 + lq)*64 + xo];
      s0h = MFMA32(kh0, qfh[st].v, s0h);
      s1h = MFMA32(kh1, qfh[st].v, s1h);
      s0l = MFMA32(kh0, qfl[st].v, s0l);
      s1l = MFMA32(kh1, qfl[st].v, s1l);
    }

    // chain-merge + mask + exp (add + fma + exp2 + cndmask), z unrounded
    #pragma unroll
    for (int r=0;r<16;r++){
      float t0 = __builtin_fmaf(s0h[r] + s0l[r], C1, nrmc);
      float t1 = __builtin_fmaf(s1h[r] + s1l[r], C1, nrmc);
      float e0 = __builtin_amdgcn_exp2f(t0);
      float e1 = __builtin_amdgcn_exp2f(t1);
      e0 = (t0 > 0.f) ? e0 : 0.f;
      e1 = (t1 > 0.f) ? e1 : 0.f;
      za += e0; zb += e1;
      s0h[r] = e0; s1h[r] = e1;
    }

    // pack P into PV A-frags (cvt_pk RNE + permlane32_swap; verified layout)
    bf16x8 pa[4];
    #pragma unroll
    for (int g=0; g<2; g++){
      const floatx16& sp = g ? s1h : s0h;
      #pragma unroll
      for (int sg=0; sg<2; sg++){
        uint X0,X1,X2,X3;
        asm("v_cvt_pk_bf16_f32 %0, %1, %2" : "=v"(X0) : "v"(sp[sg*8+0]), "v"(sp[sg*8+1]));
        asm("v_cvt_pk_bf16_f32 %0, %1, %2" : "=v"(X1) : "v"(sp[sg*8+2]), "v"(sp[sg*8+3]));
        asm("v_cvt_pk_bf16_f32 %0, %1, %2" : "=v"(X2) : "v"(sp[sg*8+4]), "v"(sp[sg*8+5]));
        asm("v_cvt_pk_bf16_f32 %0, %1, %2" : "=v"(X3) : "v"(sp[sg*8+6]), "v"(sp[sg*8+7]));
        asm("v_permlane32_swap_b32 %0, %1" : "+v"(X0), "+v"(X2));
        asm("v_permlane32_swap_b32 %0, %1" : "+v"(X1), "+v"(X3));
        union { uint u[4]; bf16x8 v; } pu;
        pu.u[0]=X0; pu.u[1]=X1; pu.u[2]=X2; pu.u[3]=X3;
        pa[g*2+sg] = pu.v;
      }
    }

    // PV: dual chains per output block (depth 2 each); merged after k-loop
    #pragma unroll
    for (int s4=0; s4<4; s4++){
      const int xo = (((s4*2 + h) ^ (lq & 7)) << 3);
      bf16x8 vf0 = *(const bf16x8*)&VTc[(lq     )*64 + xo];
      bf16x8 vf1 = *(const bf16x8*)&VTc[(32 + lq)*64 + xo];
      if (s4 & 1){
        O0b = MFMA32(pa[s4], vf0, O0b);
        O1b = MFMA32(pa[s4], vf1, O1b);
      } else {
        O0a = MFMA32(pa[s4], vf0, O0a);
        O1a = MFMA32(pa[s4], vf1, O1a);
      }
    }

    __syncthreads();   // single barrier: buf reads done + buf^1 stages drained
    cur ^= 1;
  }

  // merge PV chains once
  floatx16 O0, O1;
  #pragma unroll
  for (int r=0;r<16;r++){ O0[r] = O0a[r] + O0b[r]; O1[r] = O1a[r] + O1b[r]; }

  // cross-half combine: partial (O,z) add via LDS (reuse tile space)
  float zacc = za + zb;
  zacc += __shfl_xor(zacc, 32);
  float* CB = (float*)&TILES[0][0][0][0];
  const int ci = (ws*64 + l)*34;
  if (half == 1){
    #pragma unroll
    for (int i=0;i<16;i++){ CB[ci+i] = O0[i]; CB[ci+16+i] = O1[i]; }
    CB[ci+32] = zacc;
  }
  __syncthreads();
  if (half == 0){
    const float zinv = 1.f / (zacc + CB[ci+32]);
    #pragma unroll
    for (int r=0;r<16;r++){ O0[r] += CB[ci+r]; O1[r] += CB[ci+16+r]; }
    #pragma unroll
    for (int r=0;r<16;r++){
      const int crow = (r&3) + ((r>>2)<<3) + (h<<2);
      const float zi = __shfl(zinv, crow);
      const int q = q0 + ws*32 + crow;
      const size_t base = cb + (size_t)q*64 + lq;
      attno[base]      = f2b(O0[r] * zi);
      attno[base + 32] = f2b(O1[r] * zi);
    }
  }
}

// ---------------------------------------------------------------------------
// O-projection, plain 1-MFMA: out[m][n] = attno[m][:] . owh[n][:] + o_b[n].
// ---------------------------------------------------------------------------
__global__ __launch_bounds__(256) void proj_out(
    const ushort* __restrict__ attno, const ushort* __restrict__ owh,
    const float* __restrict__ o_b, float* __restrict__ outf)
{
  const int id = blockIdx.x;
  const int m0 = ((id & 7) * 8 + ((id >> 3) & 7)) * 64;
  const int n0 = (id >> 6) * 64;

  __shared__ __align__(16) ushort AH[2][4096];
  __shared__ __align__(16) ushort BH[2][4096];

  const int t    = threadIdx.x;
  const int lane = t & 63;
  const int w    = t >> 6;
  const int wm   = w >> 1, wn = w & 1;
  const int lr   = lane & 15, lg = lane >> 4;

  const int rl  = lane >> 3;
  const int c8s = (lane & 7) ^ rl;

  auto stage = [&](int buf, int k0){
    #pragma unroll
    for (int j = 0; j < 4; j++){
      const int c = w * 4 + j;
      if (c < 8)
        gload16(attno + (size_t)(m0 + c*8 + rl)*512 + k0 + c8s*8, &AH[buf][c*512]);
      else
        gload16(owh + (size_t)(n0 + (c-8)*8 + rl)*512 + k0 + c8s*8, &BH[buf][(c-8)*512]);
    }
  };

  floatx4 zf; zf[0]=0.f; zf[1]=0.f; zf[2]=0.f; zf[3]=0.f;
  floatx4 acc[2][2];
  #pragma unroll
  for (int i=0;i<2;i++)
    #pragma unroll
    for (int j=0;j<2;j++) acc[i][j] = zf;

  stage(0, 0);
  __syncthreads();

  int cur = 0;
  for (int it = 0; it < 8; ++it){
    if (it < 7) stage(cur^1, (it+1)*64);

    #pragma unroll
    for (int ks=0; ks<2; ks++){
      const int xo = ((ks*4 + lg) ^ (lr & 7)) << 3;
      bf16x8 ah[2], bh[2];
      #pragma unroll
      for (int mi=0;mi<2;mi++)
        ah[mi] = *(const bf16x8*)&AH[cur][(wm*32 + mi*16 + lr)*64 + xo];
      #pragma unroll
      for (int ni=0;ni<2;ni++)
        bh[ni] = *(const bf16x8*)&BH[cur][(wn*32 + ni*16 + lr)*64 + xo];
      #pragma unroll
      for (int mi=0;mi<2;mi++)
        #pragma unroll
        for (int ni=0;ni<2;ni++)
          acc[mi][ni] = MFMA16(ah[mi], bh[ni], acc[mi][ni]);
    }
    __syncthreads();
    cur ^= 1;
  }

  #pragma unroll
  for (int ni=0;ni<2;ni++){
    const int n = n0 + wn*32 + ni*16 + lr;
    const float bn = o_b[n];
    #pragma unroll
    for (int mi=0;mi<2;mi++){
      #pragma unroll
      for (int r=0;r<4;r++){
        const int m = m0 + wm*32 + mi*16 + lg*4 + r;
        outf[(size_t)m*512 + n] = acc[mi][ni][r] + bn;
      }
    }
  }
}

// ---------------------------------------------------------------------------
extern "C" void kernel_launch(void* const* d_in, const int* in_sizes, int n_in,
                              void* d_out, int out_size, void* d_ws, size_t ws_size,
                              hipStream_t stream)
{
  const float* x   = (const float*)d_in[0];
  const float* y   = (const float*)d_in[1];
  const float* q_w = (const float*)d_in[2];
  const float* q_b = (const float*)d_in[3];
  const float* k_w = (const float*)d_in[4];
  const float* k_b = (const float*)d_in[5];
  const float* v_w = (const float*)d_in[6];
  const float* v_b = (const float*)d_in[7];
  const float* o_w = (const float*)d_in[8];
  const float* o_b = (const float*)d_in[9];

  const size_t NE = 4096ull * 512;     // 2,097,152
  const size_t WN = 512ull * 512;      // 262,144
  ushort* p = (ushort*)d_ws;
  ushort* pq_hi = p;                   // projections
  ushort* pq_lo = pq_hi + NE;
  ushort* pk    = pq_lo + NE;          // plain bf16 K
  ushort* pv    = pk + NE;
  ushort* xhi   = pv + NE;             // 4 x NE: split inputs (16MB)
  ushort* xlo   = xhi + NE;
  ushort* yhi   = xlo + NE;
  ushort* ylo   = yhi + NE;
  ushort* attno = xhi;                 // alias: xhi dead after proj_qkv
  ushort* qwh = ylo + NE;              // weights (3MB)
  ushort* qwl = qwh + WN;
  ushort* kwh = qwl + WN;
  ushort* kwl = kwh + WN;
  ushort* vwh = kwl + WN;
  ushort* owh = vwh + WN;
  float*  ksumb = (float*)(owh + WN);  // 4KB
  ushort* vtg   = (ushort*)(ksumb + 1024);   // 4MB

  hipMemsetAsync(ksumb, 0, 16 * 64 * sizeof(float), stream);

  split_all<<<5120, 256, 0, stream>>>(x, y, q_w, k_w, v_w, o_w,
                                      xhi, xlo, yhi, ylo,
                                      qwh, qwl, kwh, kwl, vwh, owh);
  proj_qkv<<<1536, 256, 0, stream>>>(xhi, xlo, yhi, ylo,
                                     qwh, qwl, kwh, kwl, vwh,
                                     q_b, k_b, v_b,
                                     pq_hi, pq_lo, pk, pv, ksumb);
  vtrans<<<dim3(32,16), 256, 0, stream>>>(pv, vtg);
  attn_kernel<<<256, 512, 0, stream>>>(pq_hi, pq_lo, pk, vtg, ksumb, attno);
  proj_out<<<512, 256, 0, stream>>>(attno, owh, o_b, (float*)d_out);
}

// Round 19
// 90.752 us; speedup vs baseline: 1.0343x; 1.0343x over previous
//
#include <hip/hip_runtime.h>

// Mutihead_Attention: x,y [2,2048,512] f32. Flat-reshape => head-batch hb owns
// contiguous [2048,64] chunk at hb*131072 of each [4096,512] projection.
// scores=QK^T/sqrt(512); mask score<=rowmean; softmax; PV; @o_w^T+o_b.
// rowmean_i = q_i.ksum/2048 (ksum fused in K-proj epilogue, f32 acc).
// R19 = R17 verbatim (best verified: 90.8us, absmax 4.64e-3). R18's ILP
// reorder (4-chain QK^T, dual-O PV) regressed +3us: +48 live accumulator
// regs at the 2-wave operating point cost more than chain-depth saved.
// Composition is at its practical floor: all structural levers (LDS 32-96KB,
// 1-2 barriers, 256/512-thr blocks, kv-split 1/2/4, 84-116 VGPR, setprio,
// chain depth) measured null/negative around attn ~39-50us.
// K stored as PLAIN bf16 (projection still split x split, rounded once):
// QK^T 16 MFMA/tile, Q split hi/lo so only one operand rounded.

typedef unsigned short ushort;
typedef unsigned int uint;

typedef __bf16  bf16x8   __attribute__((ext_vector_type(8)));
typedef float   floatx4  __attribute__((ext_vector_type(4)));
typedef float   floatx16 __attribute__((ext_vector_type(16)));
typedef float   float4v  __attribute__((ext_vector_type(4)));
typedef uint    uint4v   __attribute__((ext_vector_type(4)));
typedef ushort  ushort4v __attribute__((ext_vector_type(4)));

#define MFMA16(a,b,c) __builtin_amdgcn_mfma_f32_16x16x32_bf16((a),(b),(c),0,0,0)
#define MFMA32(a,b,c) __builtin_amdgcn_mfma_f32_32x32x16_bf16((a),(b),(c),0,0,0)

__device__ __forceinline__ float b2f(ushort u){
  union { uint i; float f; } v; v.i = ((uint)u) << 16; return v.f;
}
__device__ __forceinline__ ushort f2b(float f){   // RNE f32->bf16
  union { float f; uint i; } v; v.f = f;
  uint r = v.i + 0x7FFFu + ((v.i >> 16) & 1u);
  return (ushort)(r >> 16);
}
__device__ __forceinline__ void split2(float f, ushort& h, ushort& l){
  h = f2b(f);
  l = f2b(f - b2f(h));
}
__device__ __forceinline__ void gload16(const ushort* g, ushort* l){
  __builtin_amdgcn_global_load_lds(
      (const __attribute__((address_space(1))) unsigned int*)g,
      (__attribute__((address_space(3))) unsigned int*)l, 16, 0, 0);
}

// ---------------------------------------------------------------------------
// One-time f32 -> bf16 converters, all inputs in one launch.
// ---------------------------------------------------------------------------
__global__ __launch_bounds__(256) void split_all(
    const float* __restrict__ x, const float* __restrict__ y,
    const float* __restrict__ qw, const float* __restrict__ kw,
    const float* __restrict__ vw, const float* __restrict__ ow,
    ushort* __restrict__ xhi, ushort* __restrict__ xlo,
    ushort* __restrict__ yhi, ushort* __restrict__ ylo,
    ushort* __restrict__ qwh, ushort* __restrict__ qwl,
    ushort* __restrict__ kwh, ushort* __restrict__ kwl,
    ushort* __restrict__ vwh, ushort* __restrict__ owh)
{
  int idx = blockIdx.x * 256 + threadIdx.x;       // 1,310,720 float4s total
  if (idx < 1048576){
    const float* sp; ushort *hp, *lp; int i;
    if (idx < 524288){ sp = x; hp = xhi; lp = xlo; i = idx; }
    else             { sp = y; hp = yhi; lp = ylo; i = idx - 524288; }
    float4v d = ((const float4v*)sp)[i];
    ushort4v h, l;
    #pragma unroll
    for (int j=0;j<4;j++){ ushort hh,ll; split2(d[j],hh,ll); h[j]=hh; l[j]=ll; }
    ((ushort4v*)hp)[i] = h;
    ((ushort4v*)lp)[i] = l;
  } else {
    int k = idx - 1048576;                        // 0..262143
    int a = k >> 16, i = k & 65535;
    if (a < 2){
      const float* sp = a ? kw : qw;
      ushort *hp = a ? kwh : qwh, *lp = a ? kwl : qwl;
      float4v d = ((const float4v*)sp)[i];
      ushort4v h, l;
      #pragma unroll
      for (int j=0;j<4;j++){ ushort hh,ll; split2(d[j],hh,ll); h[j]=hh; l[j]=ll; }
      ((ushort4v*)hp)[i] = h;
      ((ushort4v*)lp)[i] = l;
    } else {
      const float* sp = (a == 2) ? vw : ow;
      ushort *hp = (a == 2) ? vwh : owh;
      float4v d = ((const float4v*)sp)[i];
      ushort4v h;
      #pragma unroll
      for (int j=0;j<4;j++) h[j] = f2b(d[j]);
      ((ushort4v*)hp)[i] = h;
    }
  }
}

// ---------------------------------------------------------------------------
// Q/K/V projections in ONE dispatch. grid 1536: seg = id>>9 (0=Q,1=K,2=V).
// seg 0: split x split (3 MFMA), hi/lo out. seg 1: split x split, PLAIN bf16
// out + fused ksum (f32 acc). seg 2: plain x plain (1 MFMA), bf16 out.
// BM=64 BN=64 BK=64, XCD swizzle, dbuf, gload_lds(16), row&7 XOR swizzle.
// ---------------------------------------------------------------------------
__global__ __launch_bounds__(256) void proj_qkv(
    const ushort* __restrict__ xhi, const ushort* __restrict__ xlo,
    const ushort* __restrict__ yhi, const ushort* __restrict__ ylo,
    const ushort* __restrict__ qwh, const ushort* __restrict__ qwl,
    const ushort* __restrict__ kwh, const ushort* __restrict__ kwl,
    const ushort* __restrict__ vwh,
    const float* __restrict__ q_b, const float* __restrict__ k_b,
    const float* __restrict__ v_b,
    ushort* __restrict__ pq_hi, ushort* __restrict__ pq_lo,
    ushort* __restrict__ pk,
    ushort* __restrict__ pv, float* __restrict__ ksum_out)
{
  const int seg = blockIdx.x >> 9;
  const int id  = blockIdx.x & 511;
  const int m0 = ((id & 7) * 8 + ((id >> 3) & 7)) * 64;
  const int n0 = (id >> 6) * 64;
  const bool split = (seg < 2);

  const ushort* Ahi = (seg == 0) ? xhi : yhi;
  const ushort* Alo = (seg == 0) ? xlo : ylo;
  const ushort* Bhi = (seg == 0) ? qwh : ((seg == 1) ? kwh : vwh);
  const ushort* Blo = (seg == 0) ? qwl : kwl;
  const float*  bias = (seg == 0) ? q_b : ((seg == 1) ? k_b : v_b);
  ushort* outhi = (seg == 0) ? pq_hi : ((seg == 1) ? pk : pv);
  ushort* outlo = pq_lo;                       // used only by seg 0

  __shared__ __align__(16) ushort AH[2][4096];                 // [64][64]
  __shared__ __align__(16) ushort AL[2][4096];
  __shared__ __align__(16) ushort BH[2][4096];
  __shared__ __align__(16) ushort BL[2][4096];
  __shared__ float cs[64];

  const int t    = threadIdx.x;
  const int lane = t & 63;
  const int w    = t >> 6;
  const int wm   = w >> 1, wn = w & 1;
  const int lr   = lane & 15, lg = lane >> 4;

  const int rl  = lane >> 3;
  const int c8s = (lane & 7) ^ rl;       // pre-swizzled source 16B block

  auto stage = [&](int buf, int k0){
    if (split){
      #pragma unroll
      for (int j = 0; j < 8; j++){
        const int c = w * 8 + j;
        if (c < 8)
          gload16(Ahi + (size_t)(m0 + c*8 + rl)*512 + k0 + c8s*8, &AH[buf][c*512]);
        else if (c < 16)
          gload16(Alo + (size_t)(m0 + (c-8)*8 + rl)*512 + k0 + c8s*8, &AL[buf][(c-8)*512]);
        else if (c < 24)
          gload16(Bhi + (size_t)(n0 + (c-16)*8 + rl)*512 + k0 + c8s*8, &BH[buf][(c-16)*512]);
        else
          gload16(Blo + (size_t)(n0 + (c-24)*8 + rl)*512 + k0 + c8s*8, &BL[buf][(c-24)*512]);
      }
    } else {
      #pragma unroll
      for (int j = 0; j < 4; j++){
        const int c = w * 4 + j;
        if (c < 8)
          gload16(Ahi + (size_t)(m0 + c*8 + rl)*512 + k0 + c8s*8, &AH[buf][c*512]);
        else
          gload16(Bhi + (size_t)(n0 + (c-8)*8 + rl)*512 + k0 + c8s*8, &BH[buf][(c-8)*512]);
      }
    }
  };

  floatx4 zf; zf[0]=0.f; zf[1]=0.f; zf[2]=0.f; zf[3]=0.f;
  floatx4 acc[2][2];
  #pragma unroll
  for (int i=0;i<2;i++)
    #pragma unroll
    for (int j=0;j<2;j++) acc[i][j] = zf;

  stage(0, 0);
  __syncthreads();

  int cur = 0;
  for (int it = 0; it < 8; ++it){
    if (it < 7) stage(cur^1, (it+1)*64);

    #pragma unroll
    for (int ks=0; ks<2; ks++){
      const int xo = ((ks*4 + lg) ^ (lr & 7)) << 3;
      bf16x8 ah[2], al[2], bh[2], bl[2];
      #pragma unroll
      for (int mi=0;mi<2;mi++){
        const int off = (wm*32 + mi*16 + lr)*64 + xo;
        ah[mi] = *(const bf16x8*)&AH[cur][off];
        if (split) al[mi] = *(const bf16x8*)&AL[cur][off];
      }
      #pragma unroll
      for (int ni=0;ni<2;ni++){
        const int off = (wn*32 + ni*16 + lr)*64 + xo;
        bh[ni] = *(const bf16x8*)&BH[cur][off];
        if (split) bl[ni] = *(const bf16x8*)&BL[cur][off];
      }
      #pragma unroll
      for (int mi=0;mi<2;mi++)
        #pragma unroll
        for (int ni=0;ni<2;ni++){
          acc[mi][ni] = MFMA16(ah[mi], bh[ni], acc[mi][ni]);
          if (split){
            acc[mi][ni] = MFMA16(ah[mi], bl[ni], acc[mi][ni]);
            acc[mi][ni] = MFMA16(al[mi], bh[ni], acc[mi][ni]);
          }
        }
    }
    __syncthreads();
    cur ^= 1;
  }

  // epilogue: D frag -> m = lg*4+r, n = lr
  #pragma unroll
  for (int ni=0;ni<2;ni++){
    const int n = n0 + wn*32 + ni*16 + lr;
    const float bn = bias[n];
    #pragma unroll
    for (int mi=0;mi<2;mi++){
      #pragma unroll
      for (int r=0;r<4;r++){
        const int m = m0 + wm*32 + mi*16 + lg*4 + r;
        const float c = acc[mi][ni][r] + bn;
        const size_t off = (size_t)m*512 + n;
        if (seg == 0){ ushort h,l; split2(c,h,l); outhi[off]=h; outlo[off]=l; }
        else         { outhi[off] = f2b(c); }
      }
    }
  }

  if (seg == 1) {
    if (t < 64) cs[t] = 0.f;
    __syncthreads();
    #pragma unroll
    for (int ni=0;ni<2;ni++){
      float s = 0.f;
      #pragma unroll
      for (int mi=0;mi<2;mi++)
        #pragma unroll
        for (int r=0;r<4;r++) s += acc[mi][ni][r];
      atomicAdd(&cs[wn*32 + ni*16 + lr], s);
    }
    __syncthreads();
    if (t < 64){
      const int hb = m0 >> 8;
      atomicAdd(&ksum_out[hb*64 + t], cs[t] + 64.f * bias[n0 + t]);
    }
  }
}

// ---------------------------------------------------------------------------
// vt[hb][d][s] = pv_chunk[hb][s][d]  (64x64 LDS-tiled transpose)
// ---------------------------------------------------------------------------
__global__ __launch_bounds__(256) void vtrans(
    const ushort* __restrict__ pv, ushort* __restrict__ vt)
{
  const int hb = blockIdx.y;
  const int s0 = blockIdx.x * 64;
  const size_t cb = (size_t)hb * 131072;
  __shared__ __align__(16) ushort T[64][68];
  const int t = threadIdx.x;
  {
    int s = t >> 2, c = (t & 3) * 16;
    *(uint4v*)&T[s][c]     = *(const uint4v*)&pv[cb + (size_t)(s0+s)*64 + c];
    *(uint4v*)&T[s][c + 8] = *(const uint4v*)&pv[cb + (size_t)(s0+s)*64 + c + 8];
  }
  __syncthreads();
  const int d = t >> 2, sc = (t & 3) * 16;
  ushort buf[16];
  #pragma unroll
  for (int i=0;i<16;i++) buf[i] = T[sc + i][d];
  *(uint4v*)&vt[cb + (size_t)d*2048 + s0 + sc]     = *(const uint4v*)&buf[0];
  *(uint4v*)&vt[cb + (size_t)d*2048 + s0 + sc + 8] = *(const uint4v*)&buf[8];
}

// ---------------------------------------------------------------------------
// Fused attention (R17, best verified): 128 q-rows/block, 8 waves = 4
// q-groups (32 q each, 32x32x16 MFMA, swapped QK^T) x 2 kv-halves.
// KH/VT dbuf in 64KB LDS, single barrier/tile. QK^T = 16 MFMA/tile
// (kh x {qhi,qlo}). Cross-half (O,z) combine in LDS; normalize in-kernel.
// ---------------------------------------------------------------------------
__device__ __forceinline__ void stage_tile(
    ushort* khb, ushort* vtb,
    const ushort* gk, const ushort* gvt,
    size_t cb, int kvb, int ws, int l)
{
  const int rsub = l >> 3;
  const int c8   = (l & 7) ^ rsub;
  #pragma unroll
  for (int j = 0; j < 4; j++){
    const int chunk = ws*4 + j;       // 16 x 1KB: 8 KH, 8 VT
    const int a   = chunk >> 3;
    const int sub = chunk & 7;
    const int row = sub*8 + rsub;
    if (a == 0)
      gload16(gk  + cb + (size_t)(kvb + row)*64 + c8*8, khb + sub*512);
    else
      gload16(gvt + cb + (size_t)row*2048 + kvb + c8*8, vtb + sub*512);
  }
}

__global__ __launch_bounds__(512) void attn_kernel(
    const ushort* __restrict__ qhi, const ushort* __restrict__ qlo,
    const ushort* __restrict__ kbf,
    const ushort* __restrict__ vt,  const float* __restrict__ ksum,
    ushort* __restrict__ attno)
{
  const int id = blockIdx.x;                      // XCD swizzle: 2 hb per XCD
  const int hb = ((id & 7) << 1) | ((id >> 3) & 1);
  const int q0 = (id >> 4) * 128;
  const size_t cb = (size_t)hb * 131072;
  const float C1 = 0.04419417382415922f * 1.44269504088896f;  // NF*log2(e)

  __shared__ __align__(16) ushort TILES[2][2][2][4096];  // [half][buf][KH,VT]

  const int t = threadIdx.x, l = t & 63, w = t >> 6;
  const int half = w >> 2, ws = w & 3;
  const int lq = l & 31, h = l >> 5;
  const int kbase = half * 1024;

  stage_tile(TILES[half][0][0], TILES[half][0][1],
             kbf, vt, cb, kbase, ws, l);

  // Q frags (swapped-B operand): lane holds Q[q = lq][d = st*16 + h*8 + 0..7]
  union U8 { bf16x8 v; ushort u[8]; };
  U8 qfh[4], qfl[4];
  float part = 0.f;
  #pragma unroll
  for (int st=0; st<4; st++){
    size_t g = cb + (size_t)(q0 + ws*32 + lq)*64 + st*16 + h*8;
    qfh[st].v = *(const bf16x8*)&qhi[g];
    qfl[st].v = *(const bf16x8*)&qlo[g];
    float4v k0 = *(const float4v*)&ksum[hb*64 + st*16 + h*8];
    float4v k1 = *(const float4v*)&ksum[hb*64 + st*16 + h*8 + 4];
    #pragma unroll
    for (int j=0;j<4;j++) part += (b2f(qfh[st].u[j])   + b2f(qfl[st].u[j]))   * k0[j];
    #pragma unroll
    for (int j=0;j<4;j++) part += (b2f(qfh[st].u[4+j]) + b2f(qfl[st].u[4+j])) * k1[j];
  }
  part += __shfl_xor(part, 32);            // both d-halves
  const float rm = part * (1.f/2048.f);    // raw row mean for q = lq
  const float nrmc = -rm * C1;

  floatx16 O0 = {0,0,0,0,0,0,0,0,0,0,0,0,0,0,0,0};
  floatx16 O1 = O0;
  float za = 0.f, zb = 0.f;

  __syncthreads();                          // tile 0 staged

  int cur = 0;
  for (int kt = 0; kt < 16; kt++){
    if (kt + 1 < 16)
      stage_tile(TILES[half][cur^1][0], TILES[half][cur^1][1],
                 kbf, vt, cb, kbase + (kt+1)*64, ws, l);

    const ushort* KHc = TILES[half][cur][0];
    const ushort* VTc = TILES[half][cur][1];

    // QK^T swapped: s_g[key][q] (q = lq lane-local); K plain, Q split
    floatx16 s0 = {0,0,0,0,0,0,0,0,0,0,0,0,0,0,0,0};
    floatx16 s1 = s0;
    #pragma unroll
    for (int st=0; st<4; st++){
      const int xo = (((st*2 + h) ^ (lq & 7)) << 3);
      bf16x8 kh0 = *(const bf16x8*)&KHc[(lq     )*64 + xo];
      bf16x8 kh1 = *(const bf16x8*)&KHc[(32 + lq)*64 + xo];
      s0 = MFMA32(kh0, qfh[st].v, s0);
      s1 = MFMA32(kh1, qfh[st].v, s1);
      s0 = MFMA32(kh0, qfl[st].v, s0);
      s1 = MFMA32(kh1, qfl[st].v, s1);
    }

    // mask + exp (fma + exp2 + cndmask), z from unrounded p
    #pragma unroll
    for (int r=0;r<16;r++){
      float t0 = __builtin_fmaf(s0[r], C1, nrmc);
      float t1 = __builtin_fmaf(s1[r], C1, nrmc);
      float e0 = __builtin_amdgcn_exp2f(t0);
      float e1 = __builtin_amdgcn_exp2f(t1);
      e0 = (t0 > 0.f) ? e0 : 0.f;
      e1 = (t1 > 0.f) ? e1 : 0.f;
      za += e0; zb += e1;
      s0[r] = e0; s1[r] = e1;
    }

    // pack P into PV A-frags (cvt_pk RNE + permlane32_swap; verified layout)
    bf16x8 pa[4];
    #pragma unroll
    for (int g=0; g<2; g++){
      const floatx16& sp = g ? s1 : s0;
      #pragma unroll
      for (int sg=0; sg<2; sg++){
        uint X0,X1,X2,X3;
        asm("v_cvt_pk_bf16_f32 %0, %1, %2" : "=v"(X0) : "v"(sp[sg*8+0]), "v"(sp[sg*8+1]));
        asm("v_cvt_pk_bf16_f32 %0, %1, %2" : "=v"(X1) : "v"(sp[sg*8+2]), "v"(sp[sg*8+3]));
        asm("v_cvt_pk_bf16_f32 %0, %1, %2" : "=v"(X2) : "v"(sp[sg*8+4]), "v"(sp[sg*8+5]));
        asm("v_cvt_pk_bf16_f32 %0, %1, %2" : "=v"(X3) : "v"(sp[sg*8+6]), "v"(sp[sg*8+7]));
        asm("v_permlane32_swap_b32 %0, %1" : "+v"(X0), "+v"(X2));
        asm("v_permlane32_swap_b32 %0, %1" : "+v"(X1), "+v"(X3));
        union { uint u[4]; bf16x8 v; } pu;
        pu.u[0]=X0; pu.u[1]=X1; pu.u[2]=X2; pu.u[3]=X3;
        pa[g*2+sg] = pu.v;
      }
    }

    // PV: O[q][d] += P[q][k] V[k][d]
    #pragma unroll
    for (int s4=0; s4<4; s4++){
      const int xo = (((s4*2 + h) ^ (lq & 7)) << 3);
      bf16x8 vf0 = *(const bf16x8*)&VTc[(lq     )*64 + xo];
      bf16x8 vf1 = *(const bf16x8*)&VTc[(32 + lq)*64 + xo];
      O0 = MFMA32(pa[s4], vf0, O0);
      O1 = MFMA32(pa[s4], vf1, O1);
    }

    __syncthreads();   // single barrier: buf reads done + buf^1 stages drained
    cur ^= 1;
  }

  // cross-half combine: partial (O,z) add via LDS (reuse tile space)
  float zacc = za + zb;
  zacc += __shfl_xor(zacc, 32);
  float* CB = (float*)&TILES[0][0][0][0];
  const int ci = (ws*64 + l)*34;
  if (half == 1){
    #pragma unroll
    for (int i=0;i<16;i++){ CB[ci+i] = O0[i]; CB[ci+16+i] = O1[i]; }
    CB[ci+32] = zacc;
  }
  __syncthreads();
  if (half == 0){
    const float zinv = 1.f / (zacc + CB[ci+32]);
    #pragma unroll
    for (int r=0;r<16;r++){ O0[r] += CB[ci+r]; O1[r] += CB[ci+16+r]; }
    #pragma unroll
    for (int r=0;r<16;r++){
      const int crow = (r&3) + ((r>>2)<<3) + (h<<2);
      const float zi = __shfl(zinv, crow);
      const int q = q0 + ws*32 + crow;
      const size_t base = cb + (size_t)q*64 + lq;
      attno[base]      = f2b(O0[r] * zi);
      attno[base + 32] = f2b(O1[r] * zi);
    }
  }
}

// ---------------------------------------------------------------------------
// O-projection, plain 1-MFMA: out[m][n] = attno[m][:] . owh[n][:] + o_b[n].
// Both operands bf16, staged via gload_lds(16), dbuf, XOR swizzle. f32 out.
// ---------------------------------------------------------------------------
__global__ __launch_bounds__(256) void proj_out(
    const ushort* __restrict__ attno, const ushort* __restrict__ owh,
    const float* __restrict__ o_b, float* __restrict__ outf)
{
  const int id = blockIdx.x;
  const int m0 = ((id & 7) * 8 + ((id >> 3) & 7)) * 64;
  const int n0 = (id >> 6) * 64;

  __shared__ __align__(16) ushort AH[2][4096];
  __shared__ __align__(16) ushort BH[2][4096];

  const int t    = threadIdx.x;
  const int lane = t & 63;
  const int w    = t >> 6;
  const int wm   = w >> 1, wn = w & 1;
  const int lr   = lane & 15, lg = lane >> 4;

  const int rl  = lane >> 3;
  const int c8s = (lane & 7) ^ rl;

  auto stage = [&](int buf, int k0){
    #pragma unroll
    for (int j = 0; j < 4; j++){
      const int c = w * 4 + j;
      if (c < 8)
        gload16(attno + (size_t)(m0 + c*8 + rl)*512 + k0 + c8s*8, &AH[buf][c*512]);
      else
        gload16(owh + (size_t)(n0 + (c-8)*8 + rl)*512 + k0 + c8s*8, &BH[buf][(c-8)*512]);
    }
  };

  floatx4 zf; zf[0]=0.f; zf[1]=0.f; zf[2]=0.f; zf[3]=0.f;
  floatx4 acc[2][2];
  #pragma unroll
  for (int i=0;i<2;i++)
    #pragma unroll
    for (int j=0;j<2;j++) acc[i][j] = zf;

  stage(0, 0);
  __syncthreads();

  int cur = 0;
  for (int it = 0; it < 8; ++it){
    if (it < 7) stage(cur^1, (it+1)*64);

    #pragma unroll
    for (int ks=0; ks<2; ks++){
      const int xo = ((ks*4 + lg) ^ (lr & 7)) << 3;
      bf16x8 ah[2], bh[2];
      #pragma unroll
      for (int mi=0;mi<2;mi++)
        ah[mi] = *(const bf16x8*)&AH[cur][(wm*32 + mi*16 + lr)*64 + xo];
      #pragma unroll
      for (int ni=0;ni<2;ni++)
        bh[ni] = *(const bf16x8*)&BH[cur][(wn*32 + ni*16 + lr)*64 + xo];
      #pragma unroll
      for (int mi=0;mi<2;mi++)
        #pragma unroll
        for (int ni=0;ni<2;ni++)
          acc[mi][ni] = MFMA16(ah[mi], bh[ni], acc[mi][ni]);
    }
    __syncthreads();
    cur ^= 1;
  }

  #pragma unroll
  for (int ni=0;ni<2;ni++){
    const int n = n0 + wn*32 + ni*16 + lr;
    const float bn = o_b[n];
    #pragma unroll
    for (int mi=0;mi<2;mi++){
      #pragma unroll
      for (int r=0;r<4;r++){
        const int m = m0 + wm*32 + mi*16 + lg*4 + r;
        outf[(size_t)m*512 + n] = acc[mi][ni][r] + bn;
      }
    }
  }
}

// ---------------------------------------------------------------------------
extern "C" void kernel_launch(void* const* d_in, const int* in_sizes, int n_in,
                              void* d_out, int out_size, void* d_ws, size_t ws_size,
                              hipStream_t stream)
{
  const float* x   = (const float*)d_in[0];
  const float* y   = (const float*)d_in[1];
  const float* q_w = (const float*)d_in[2];
  const float* q_b = (const float*)d_in[3];
  const float* k_w = (const float*)d_in[4];
  const float* k_b = (const float*)d_in[5];
  const float* v_w = (const float*)d_in[6];
  const float* v_b = (const float*)d_in[7];
  const float* o_w = (const float*)d_in[8];
  const float* o_b = (const float*)d_in[9];

  const size_t NE = 4096ull * 512;     // 2,097,152
  const size_t WN = 512ull * 512;      // 262,144
  ushort* p = (ushort*)d_ws;
  ushort* pq_hi = p;                   // projections
  ushort* pq_lo = pq_hi + NE;
  ushort* pk    = pq_lo + NE;          // plain bf16 K
  ushort* pv    = pk + NE;
  ushort* xhi   = pv + NE;             // 4 x NE: split inputs (16MB)
  ushort* xlo   = xhi + NE;
  ushort* yhi   = xlo + NE;
  ushort* ylo   = yhi + NE;
  ushort* attno = xhi;                 // alias: xhi dead after proj_qkv
  ushort* qwh = ylo + NE;              // weights (3MB)
  ushort* qwl = qwh + WN;
  ushort* kwh = qwl + WN;
  ushort* kwl = kwh + WN;
  ushort* vwh = kwl + WN;
  ushort* owh = vwh + WN;
  float*  ksumb = (float*)(owh + WN);  // 4KB
  ushort* vtg   = (ushort*)(ksumb + 1024);   // 4MB

  hipMemsetAsync(ksumb, 0, 16 * 64 * sizeof(float), stream);

  split_all<<<5120, 256, 0, stream>>>(x, y, q_w, k_w, v_w, o_w,
                                      xhi, xlo, yhi, ylo,
                                      qwh, qwl, kwh, kwl, vwh, owh);
  proj_qkv<<<1536, 256, 0, stream>>>(xhi, xlo, yhi, ylo,
                                     qwh, qwl, kwh, kwl, vwh,
                                     q_b, k_b, v_b,
                                     pq_hi, pq_lo, pk, pv, ksumb);
  vtrans<<<dim3(32,16), 256, 0, stream>>>(pv, vtg);
  attn_kernel<<<256, 512, 0, stream>>>(pq_hi, pq_lo, pk, vtg, ksumb, attno);
  proj_out<<<512, 256, 0, stream>>>(attno, owh, o_b, (float*)d_out);
}